// Round 2
// baseline (154.408 us; speedup 1.0000x reference)
//
#include <hip/hip_runtime.h>

// ApproxNDCGLoss, N=20000, fp32 — ONE dispatch, minimal-traffic grid barrier.
//
// Round-1 post-mortem: fused kernel was 60 us, VALUBusy 1.6%, FETCH 840 KB
// (5x input). Cause: (a) acquire-load spin => buffer_inv L2 invalidate per
// poll x 64 blocks = fabric storm + refetch; (b) missing __syncthreads before
// block 0's barrier arrive => g_ybkt scatter race (absmax 4.9e-4).
//
// This version: cross-block traffic is ONLY g_nodef[64] + g_bar/g_done/g_acc.
//  - Block 0: counting sort (hist/scan in LDS, ybkt in block-private global)
//    AND the full idcg+ysum computation locally (plain ops + __syncthreads;
//    no cross-block visibility of sort data needed at all).
//  - Blocks 1..64: Chebyshev node F_k (identical math to the verified round-0
//    kernel); tid0 publishes F_k via agent-scope write-through atomic store.
//  - Barrier: release fetch_add; RELAXED spin + s_sleep (no invalidates);
//    one acquire fence on exit. Readers use agent-scope relaxed loads
//    (bypass per-XCD L2 => no staleness without invalidates).
//  - dcg (barycentric) spread over all 65 blocks in ~308-elem chunks.
// State self-cleans in the finalize for the next graph replay.

#define LOG2E 1.442695040888963387f
#define M_NODES 64
#define XHALF 8.0
#define NB 2048
#define PI_D 3.14159265358979323846
#define BT 1024
#define GBLKS (M_NODES + 1)  // 65 blocks: 0 = sort+idcg, 1..64 = nodes
#define MAXN 131072

#if __has_builtin(__builtin_amdgcn_exp2f)
#define EXP2(x) __builtin_amdgcn_exp2f(x)
#else
#define EXP2(x) exp2f(x)
#endif

#if __has_builtin(__builtin_amdgcn_rcpf)
#define RCP(x) __builtin_amdgcn_rcpf(x)
#else
#define RCP(x) (1.0f / (x))
#endif

// ---- module-global state ----
__device__ double g_acc[3] = {0.0, 0.0, 0.0};  // dcg, idcg, ysum
__device__ int g_done = 0;
__device__ int g_bar = 0;
__device__ float g_nodef[M_NODES];  // the ONLY cross-block data array
__device__ float g_ybkt[MAXN];      // block-0-PRIVATE scratch (never crosses)

__device__ __forceinline__ int bucket_of(float y) {
  int b = (int)(y * (float)NB);
  return b < 0 ? 0 : (b > NB - 1 ? NB - 1 : b);
}

// agent-scope atomics: bypass per-XCD L2, serialize at the coherence point
__device__ __forceinline__ float aloadf(const float* p) {
  return __hip_atomic_load(p, __ATOMIC_RELAXED, __HIP_MEMORY_SCOPE_AGENT);
}
__device__ __forceinline__ void astoref(float* p, float v) {
  __hip_atomic_store(p, v, __ATOMIC_RELAXED, __HIP_MEMORY_SCOPE_AGENT);
}

__global__ __launch_bounds__(BT) void fused_kernel(
    const float* __restrict__ s, const float* __restrict__ y,
    float* __restrict__ out, int n) {
  const int tid = threadIdx.x;
  const int blk = blockIdx.x;

  __shared__ int hist[NB];        // histogram, then scatter cursor
  __shared__ int part[BT];        // scan partials
  __shared__ int prefix[NB + 1];  // bucket starts (block 0 only)
  __shared__ float2 nd[M_NODES];  // dc phase node table
  __shared__ double wsum[16];     // block reduction scratch

  // ---------------- phase 1 ----------------
  if (blk == 0) {
    // counting sort of y (block-local)
    for (int b = tid; b < NB; b += BT) hist[b] = 0;
    __syncthreads();

    const float4* y4 = (const float4*)y;
    const int n4 = n >> 2;
    for (int i = tid; i < n4; i += BT) {
      const float4 v = y4[i];
      atomicAdd(&hist[bucket_of(v.x)], 1);
      atomicAdd(&hist[bucket_of(v.y)], 1);
      atomicAdd(&hist[bucket_of(v.z)], 1);
      atomicAdd(&hist[bucket_of(v.w)], 1);
    }
    for (int i = (n4 << 2) + tid; i < n; i += BT)
      atomicAdd(&hist[bucket_of(y[i])], 1);
    __syncthreads();

    // exclusive scan: 2 bins/thread + Hillis-Steele over 1024
    const int base = tid * 2;
    const int l0 = hist[base], l1 = hist[base + 1];
    const int sum2 = l0 + l1;
    part[tid] = sum2;
    __syncthreads();
    for (int off = 1; off < BT; off <<= 1) {
      const int v = (tid >= off) ? part[tid - off] : 0;
      __syncthreads();
      part[tid] += v;
      __syncthreads();
    }
    const int run = part[tid] - sum2;
    prefix[base] = run;
    prefix[base + 1] = run + l0;
    if (tid == BT - 1) prefix[NB] = run + sum2;  // == n
    __syncthreads();
    hist[base] = run;  // cursor init
    hist[base + 1] = run + l0;
    __syncthreads();

    // scatter (block-private global; only this block ever reads it)
    for (int i = tid; i < n4; i += BT) {
      const float4 v = y4[i];
      g_ybkt[atomicAdd(&hist[bucket_of(v.x)], 1)] = v.x;
      g_ybkt[atomicAdd(&hist[bucket_of(v.y)], 1)] = v.y;
      g_ybkt[atomicAdd(&hist[bucket_of(v.z)], 1)] = v.z;
      g_ybkt[atomicAdd(&hist[bucket_of(v.w)], 1)] = v.w;
    }
    for (int i = (n4 << 2) + tid; i < n; i += BT) {
      const float yv = y[i];
      g_ybkt[atomicAdd(&hist[bucket_of(yv)], 1)] = yv;
    }
    __syncthreads();  // scatter complete before same-block reads (r1 race fix)

    // idcg + ysum, entirely block-local (exact rank via strict-greater count)
    double ic = 0.0, ys = 0.0;
    for (int i = tid; i < n; i += BT) {
      const float yv = y[i];
      const int b = bucket_of(yv);
      const int s0 = prefix[b], s1 = prefix[b + 1];
      int cnt = n - s1;  // strictly higher buckets
      for (int t = s0; t < s1; ++t) cnt += (g_ybkt[t] > yv);
      ic += (double)yv / log2((double)cnt + 2.0);
      ys += (double)yv;
    }
    for (int off = 32; off > 0; off >>= 1) {
      ic += __shfl_down(ic, off);
      ys += __shfl_down(ys, off);
    }
    if ((tid & 63) == 0) wsum[tid >> 6] = ic;
    __syncthreads();
    if (tid == 0) {
      double t = 0.0;
#pragma unroll
      for (int w = 0; w < 16; ++w) t += wsum[w];
      atomicAdd(&g_acc[1], t);
    }
    __syncthreads();
    if ((tid & 63) == 0) wsum[tid >> 6] = ys;
    __syncthreads();
    if (tid == 0) {
      double t = 0.0;
#pragma unroll
      for (int w = 0; w < 16; ++w) t += wsum[w];
      atomicAdd(&g_acc[2], t);
    }
  } else {
    // node k: F(x_k) = sum_i sigmoid(x_k - s_i)
    const int k = blk - 1;
    const float xk =
        (float)(XHALF * cos(PI_D * (double)k / (double)(M_NODES - 1)));
    double F = 0.0;
    const float4* s4 = (const float4*)s;
    const int n4 = n >> 2;
    for (int i = tid; i < n4; i += BT) {
      const float4 v = s4[i];
      float t = RCP(1.0f + EXP2((v.x - xk) * LOG2E));
      t += RCP(1.0f + EXP2((v.y - xk) * LOG2E));
      t += RCP(1.0f + EXP2((v.z - xk) * LOG2E));
      t += RCP(1.0f + EXP2((v.w - xk) * LOG2E));
      F += (double)t;
    }
    for (int i = (n4 << 2) + tid; i < n; i += BT)
      F += (double)RCP(1.0f + EXP2((s[i] - xk) * LOG2E));
    for (int off = 32; off > 0; off >>= 1) F += __shfl_down(F, off);
    if ((tid & 63) == 0) wsum[tid >> 6] = F;
    __syncthreads();
    if (tid == 0) {
      double t = 0.0;
#pragma unroll
      for (int w = 0; w < 16; ++w) t += wsum[w];
      astoref(&g_nodef[k], (float)t);  // write-through to coherence point
    }
  }

  // ------- grid barrier: release arrive, RELAXED spin, one acquire -------
  if (tid == 0) {
    // release: waits vmcnt(0) so the g_nodef / g_acc publications are at IF$
    __hip_atomic_fetch_add(&g_bar, 1, __ATOMIC_RELEASE,
                           __HIP_MEMORY_SCOPE_AGENT);
    while (__hip_atomic_load(&g_bar, __ATOMIC_RELAXED,
                             __HIP_MEMORY_SCOPE_AGENT) < GBLKS)
      __builtin_amdgcn_s_sleep(8);
    __builtin_amdgcn_fence(__ATOMIC_ACQUIRE, "agent");  // once per block
  }
  __syncthreads();

  // ---------------- phase 2: dcg via barycentric F(s_j) ----------------
  if (tid < M_NODES) {
    const float xk =
        (float)(XHALF * cos(PI_D * (double)tid / (double)(M_NODES - 1)));
    nd[tid] = make_float2(xk, aloadf(&g_nodef[tid]));
  }
  __syncthreads();

  const int chunk = (n + GBLKS - 1) / GBLKS;  // ~308
  const int j0 = blk * chunk;
  const int j1 = (j0 + chunk < n) ? (j0 + chunk) : n;
  double dc = 0.0;
  for (int j = j0 + tid; j < j1; j += BT) {
    const float x = s[j];
    const float yj = y[j];
    double num = 0.0, den = 0.0;
    int hit = -1;
#pragma unroll
    for (int k = 0; k < M_NODES; ++k) {
      const float d = x - nd[k].x;
      float w = (k & 1) ? -1.0f : 1.0f;
      if (k == 0 || k == M_NODES - 1) w *= 0.5f;
      if (d == 0.0f) {
        hit = k;
      } else {
        const float iv = w * RCP(d);
        num += (double)iv * (double)nd[k].y;
        den += (double)iv;
      }
    }
    const double F = (hit >= 0) ? (double)nd[hit].y : (num / den);
    dc += (double)yj / log2(F + 2.0);
  }
  for (int off = 32; off > 0; off >>= 1) dc += __shfl_down(dc, off);
  if ((tid & 63) == 0) wsum[tid >> 6] = dc;
  __syncthreads();
  if (tid == 0) {
    double a = 0.0;
#pragma unroll
    for (int w = 0; w < 16; ++w) a += wsum[w];
    atomicAdd(&g_acc[0], a);
    const int old = __hip_atomic_fetch_add(&g_done, 1, __ATOMIC_ACQ_REL,
                                           __HIP_MEMORY_SCOPE_AGENT);
    if (old == GBLKS - 1) {  // last block: all acc RMWs are at IF$
      const double dcg = atomicAdd(&g_acc[0], 0.0);
      const double idcg = atomicAdd(&g_acc[1], 0.0);
      const double yss = atomicAdd(&g_acc[2], 0.0);
      const double loss = 1.0 - dcg / (idcg + 1e-8);
      out[0] = (yss < 1.0) ? 0.0f : (float)loss;
      // self-clean for next replay (stream-serialized => no overlap)
      __hip_atomic_store(&g_acc[0], 0.0, __ATOMIC_RELAXED,
                         __HIP_MEMORY_SCOPE_AGENT);
      __hip_atomic_store(&g_acc[1], 0.0, __ATOMIC_RELAXED,
                         __HIP_MEMORY_SCOPE_AGENT);
      __hip_atomic_store(&g_acc[2], 0.0, __ATOMIC_RELAXED,
                         __HIP_MEMORY_SCOPE_AGENT);
      __hip_atomic_store(&g_done, 0, __ATOMIC_RELAXED,
                         __HIP_MEMORY_SCOPE_AGENT);
      __hip_atomic_store(&g_bar, 0, __ATOMIC_RELEASE,
                         __HIP_MEMORY_SCOPE_AGENT);
    }
  }
}

extern "C" void kernel_launch(void* const* d_in, const int* in_sizes, int n_in,
                              void* d_out, int out_size, void* d_ws,
                              size_t ws_size, hipStream_t stream) {
  const float* s = (const float*)d_in[0];
  const float* y = (const float*)d_in[1];
  const int n = in_sizes[0];
  (void)d_ws;
  (void)ws_size;  // poison is unconditional (r1 evidence) — ws unused
  fused_kernel<<<GBLKS, BT, 0, stream>>>(s, y, (float*)d_out, n);
}

// Round 3
// 125.387 us; speedup vs baseline: 1.2314x; 1.2314x over previous
//
#include <hip/hip_runtime.h>

// ApproxNDCGLoss, N=20000, fp32 — ONE dispatch, ZERO cache-maintenance ops.
//
// Round-2 post-mortem: 115 us, VALUBusy 1%, WRITE 13.4 MB / FETCH 7.4 MB.
// Cause: agent-scope release/acquire atomics & fences emit buffer_wbl2 /
// buffer_inv (full XCD-L2 writeback / invalidate) — ~130 of each per launch,
// flushing megabytes of dirty L2 (harness fill residue) and forcing s/y
// refetch. Fix: ALL cross-block data goes through RELAXED agent-scope atomics
// (sc-bits => bypass XCD L2, complete at IF$ — coherent by construction);
// ordering is s_waitcnt vmcnt(0) ONLY (a wait, not a flush). No release, no
// acquire, no fence instruction anywhere in the kernel.
//
// Load-balance fix: idcg is no longer on block 0's critical path. Block 0
// arrives at the barrier right after the scatter (prefix/ybkt published via
// relaxed agent stores); after the barrier ALL 65 blocks compute dcg AND idcg
// together per-j chunk. Scan is 2-barrier shuffle-based (was 30 barriers).
//
// Phase 1: blk 0 = 2048-bucket counting sort (hist/scan LDS, scatter->IF$);
//          blk 1..64 = F at Chebyshev-Lobatto node k (20k sigmoids, float4).
// Barrier: per-thread s_waitcnt vmcnt(0) + __syncthreads (drains every wave's
//          IF$ stores), tid0 relaxed fetch_add + relaxed spin + s_sleep.
// Phase 2: per-j barycentric F(s_j) (dcg) + exact rank count (idcg) + ysum;
//          3-way f64 block reduce; relaxed f64 atomics; vmcnt-ordered ticket
//          finalize; state self-cleans for the next graph replay.

#define LOG2E 1.442695040888963387f
#define M_NODES 64
#define XHALF 8.0
#define NB 2048
#define PI_D 3.14159265358979323846
#define BT 1024
#define GBLKS (M_NODES + 1)
#define MAXN 131072

#if __has_builtin(__builtin_amdgcn_exp2f)
#define EXP2(x) __builtin_amdgcn_exp2f(x)
#else
#define EXP2(x) exp2f(x)
#endif

#if __has_builtin(__builtin_amdgcn_rcpf)
#define RCP(x) __builtin_amdgcn_rcpf(x)
#else
#define RCP(x) (1.0f / (x))
#endif

#define WAIT_VM0() asm volatile("s_waitcnt vmcnt(0)" ::: "memory")

// ---- module-global state (all cross-block, all accessed relaxed/agent) ----
__device__ double g_acc[3] = {0.0, 0.0, 0.0};  // dcg, idcg, ysum
__device__ int g_done = 0;
__device__ int g_bar = 0;
__device__ float g_nodef[M_NODES];
__device__ int g_prefix[NB + 1];
__device__ float g_ybkt[MAXN];

__device__ __forceinline__ int bucket_of(float y) {
  int b = (int)(y * (float)NB);
  return b < 0 ? 0 : (b > NB - 1 ? NB - 1 : b);
}

// relaxed agent-scope atomics: bypass XCD L2, coherent at IF$, NO cache ops
__device__ __forceinline__ float aloadf(const float* p) {
  return __hip_atomic_load(p, __ATOMIC_RELAXED, __HIP_MEMORY_SCOPE_AGENT);
}
__device__ __forceinline__ int aloadi(const int* p) {
  return __hip_atomic_load(p, __ATOMIC_RELAXED, __HIP_MEMORY_SCOPE_AGENT);
}
__device__ __forceinline__ double aloadd(const double* p) {
  return __hip_atomic_load(p, __ATOMIC_RELAXED, __HIP_MEMORY_SCOPE_AGENT);
}
__device__ __forceinline__ void astoref(float* p, float v) {
  __hip_atomic_store(p, v, __ATOMIC_RELAXED, __HIP_MEMORY_SCOPE_AGENT);
}
__device__ __forceinline__ void astorei(int* p, int v) {
  __hip_atomic_store(p, v, __ATOMIC_RELAXED, __HIP_MEMORY_SCOPE_AGENT);
}
__device__ __forceinline__ void astored(double* p, double v) {
  __hip_atomic_store(p, v, __ATOMIC_RELAXED, __HIP_MEMORY_SCOPE_AGENT);
}
__device__ __forceinline__ void aaddd(double* p, double v) {
  __hip_atomic_fetch_add(p, v, __ATOMIC_RELAXED, __HIP_MEMORY_SCOPE_AGENT);
}
__device__ __forceinline__ int afetchaddi(int* p, int v) {
  return __hip_atomic_fetch_add(p, v, __ATOMIC_RELAXED,
                                __HIP_MEMORY_SCOPE_AGENT);
}

__global__ __launch_bounds__(BT) void fused_kernel(
    const float* __restrict__ s, const float* __restrict__ y,
    float* __restrict__ out, int n) {
  const int tid = threadIdx.x;
  const int blk = blockIdx.x;
  const int lane = tid & 63;

  __shared__ int hist[NB];        // histogram, then scatter cursor
  __shared__ int wrep[16];        // per-wave scan partials
  __shared__ float2 nd[M_NODES];  // phase-2 node table
  __shared__ double wsum[48];     // block reduction scratch

  // ---------------- phase 1 ----------------
  if (blk == 0) {
    // --- counting sort of y ---
    for (int b = tid; b < NB; b += BT) hist[b] = 0;
    __syncthreads();

    const float4* y4 = (const float4*)y;
    const int n4 = n >> 2;
    for (int i = tid; i < n4; i += BT) {
      const float4 v = y4[i];
      atomicAdd(&hist[bucket_of(v.x)], 1);
      atomicAdd(&hist[bucket_of(v.y)], 1);
      atomicAdd(&hist[bucket_of(v.z)], 1);
      atomicAdd(&hist[bucket_of(v.w)], 1);
    }
    for (int i = (n4 << 2) + tid; i < n; i += BT)
      atomicAdd(&hist[bucket_of(y[i])], 1);
    __syncthreads();

    // --- exclusive scan (2 bins/thread), shuffle-based, 2 barriers ---
    const int base = tid * 2;
    const int l0 = hist[base], l1 = hist[base + 1];
    const int sum2 = l0 + l1;
    int v = sum2;  // inclusive scan within wave
#pragma unroll
    for (int d = 1; d < 64; d <<= 1) {
      const int t = __shfl_up(v, d);
      if (lane >= d) v += t;
    }
    if (lane == 63) wrep[tid >> 6] = v;
    __syncthreads();
    if (tid < 16) {
      int wv = wrep[tid];
#pragma unroll
      for (int d = 1; d < 16; d <<= 1) {
        const int t = __shfl_up(wv, d);
        if (tid >= d) wv += t;
      }
      wrep[tid] = wv;  // inclusive wave totals
    }
    __syncthreads();
    const int wbase = (tid >> 6) ? wrep[(tid >> 6) - 1] : 0;
    const int incl = wbase + v;      // inclusive over 1024 chunks
    const int run = incl - sum2;     // exclusive prefix of this chunk
    astorei(&g_prefix[base], run);   // publish to IF$ (cross-block)
    astorei(&g_prefix[base + 1], run + l0);
    if (tid == BT - 1) astorei(&g_prefix[NB], incl);  // == n
    hist[base] = run;                // LDS scatter cursor
    hist[base + 1] = run + l0;
    __syncthreads();

    // --- scatter: values go straight to IF$ (agent stores, no L2 dirt) ---
    for (int i = tid; i < n4; i += BT) {
      const float4 v4 = y4[i];
      astoref(&g_ybkt[atomicAdd(&hist[bucket_of(v4.x)], 1)], v4.x);
      astoref(&g_ybkt[atomicAdd(&hist[bucket_of(v4.y)], 1)], v4.y);
      astoref(&g_ybkt[atomicAdd(&hist[bucket_of(v4.z)], 1)], v4.z);
      astoref(&g_ybkt[atomicAdd(&hist[bucket_of(v4.w)], 1)], v4.w);
    }
    for (int i = (n4 << 2) + tid; i < n; i += BT) {
      const float yv = y[i];
      astoref(&g_ybkt[atomicAdd(&hist[bucket_of(yv)], 1)], yv);
    }
  } else {
    // --- node k: F(x_k) = sum_i sigmoid(x_k - s_i) ---
    const int k = blk - 1;
    const float xk =
        (float)(XHALF * cos(PI_D * (double)k / (double)(M_NODES - 1)));
    double F = 0.0;
    const float4* s4 = (const float4*)s;
    const int n4 = n >> 2;
    for (int i = tid; i < n4; i += BT) {
      const float4 v = s4[i];
      float t = RCP(1.0f + EXP2((v.x - xk) * LOG2E));
      t += RCP(1.0f + EXP2((v.y - xk) * LOG2E));
      t += RCP(1.0f + EXP2((v.z - xk) * LOG2E));
      t += RCP(1.0f + EXP2((v.w - xk) * LOG2E));
      F += (double)t;
    }
    for (int i = (n4 << 2) + tid; i < n; i += BT)
      F += (double)RCP(1.0f + EXP2((s[i] - xk) * LOG2E));
    for (int off = 32; off > 0; off >>= 1) F += __shfl_down(F, off);
    if (lane == 0) wsum[tid >> 6] = F;
    __syncthreads();
    if (tid == 0) {
      double t = 0.0;
#pragma unroll
      for (int w = 0; w < 16; ++w) t += wsum[w];
      astoref(&g_nodef[k], (float)t);  // publish node sum to IF$
    }
  }

  // -------- grid barrier: drain own stores, relaxed arrive+spin ----------
  WAIT_VM0();       // every wave: its IF$ stores are complete
  __syncthreads();  // join all waves of this block
  if (tid == 0) {
    afetchaddi(&g_bar, 1);  // relaxed RMW at IF$ — no wbl2
    while (aloadi(&g_bar) < GBLKS) __builtin_amdgcn_s_sleep(16);
  }
  __syncthreads();

  // ---------------- phase 2: dcg + idcg + ysum over j-chunk ----------------
  if (tid < M_NODES) {
    const float xk =
        (float)(XHALF * cos(PI_D * (double)tid / (double)(M_NODES - 1)));
    nd[tid] = make_float2(xk, aloadf(&g_nodef[tid]));  // IF$ read — fresh
  }
  __syncthreads();

  const int chunk = (n + GBLKS - 1) / GBLKS;  // ~308
  const int j0 = blk * chunk;
  const int j1 = (j0 + chunk < n) ? (j0 + chunk) : n;
  double dc = 0.0, ic = 0.0, ys = 0.0;
  for (int j = j0 + tid; j < j1; j += BT) {
    const float x = s[j];
    const float yj = y[j];
    // dcg: barycentric interpolation of F(s_j)
    double num = 0.0, den = 0.0;
    int hit = -1;
#pragma unroll
    for (int k = 0; k < M_NODES; ++k) {
      const float d = x - nd[k].x;
      float w = (k & 1) ? -1.0f : 1.0f;
      if (k == 0 || k == M_NODES - 1) w *= 0.5f;
      if (d == 0.0f) {
        hit = k;
      } else {
        const float iv = w * RCP(d);
        num += (double)iv * (double)nd[k].y;
        den += (double)iv;
      }
    }
    const double F = (hit >= 0) ? (double)nd[hit].y : (num / den);
    dc += (double)yj / log2(F + 2.0);
    // idcg: exact rank = 1 + #(strictly greater); IF$-coherent reads
    const int b = bucket_of(yj);
    const int s0 = aloadi(&g_prefix[b]);
    const int s1 = aloadi(&g_prefix[b + 1]);
    int cnt = n - s1;  // strictly higher buckets
    for (int t = s0; t < s1; ++t) cnt += (aloadf(&g_ybkt[t]) > yj);
    ic += (double)yj / log2((double)cnt + 2.0);
    ys += (double)yj;
  }
  for (int off = 32; off > 0; off >>= 1) {
    dc += __shfl_down(dc, off);
    ic += __shfl_down(ic, off);
    ys += __shfl_down(ys, off);
  }
  const int wv = tid >> 6;
  if (lane == 0) {
    wsum[wv] = dc;
    wsum[wv + 16] = ic;
    wsum[wv + 32] = ys;
  }
  __syncthreads();
  if (tid == 0) {
    double a = 0.0, b = 0.0, c = 0.0;
#pragma unroll
    for (int w = 0; w < 16; ++w) {
      a += wsum[w];
      b += wsum[w + 16];
      c += wsum[w + 32];
    }
    aaddd(&g_acc[0], a);  // relaxed f64 RMW at IF$
    aaddd(&g_acc[1], b);
    aaddd(&g_acc[2], c);
    WAIT_VM0();  // acc RMWs complete at IF$ before the ticket
    const int old = afetchaddi(&g_done, 1);
    if (old == GBLKS - 1) {  // last block: all acc RMWs are at IF$
      const double dcg = aloadd(&g_acc[0]);
      const double idcg = aloadd(&g_acc[1]);
      const double yss = aloadd(&g_acc[2]);
      const double loss = 1.0 - dcg / (idcg + 1e-8);
      out[0] = (yss < 1.0) ? 0.0f : (float)loss;
      // self-clean for next graph replay (kernel boundary orders this)
      astored(&g_acc[0], 0.0);
      astored(&g_acc[1], 0.0);
      astored(&g_acc[2], 0.0);
      astorei(&g_done, 0);
      astorei(&g_bar, 0);
    }
  }
}

extern "C" void kernel_launch(void* const* d_in, const int* in_sizes, int n_in,
                              void* d_out, int out_size, void* d_ws,
                              size_t ws_size, hipStream_t stream) {
  const float* s = (const float*)d_in[0];
  const float* y = (const float*)d_in[1];
  const int n = in_sizes[0];
  (void)d_ws;
  (void)ws_size;  // ws poison is unconditional harness behavior — ws unused
  fused_kernel<<<GBLKS, BT, 0, stream>>>(s, y, (float*)d_out, n);
}